// Round 2
// baseline (99.469 us; speedup 1.0000x reference)
//
#include <hip/hip_runtime.h>
#include <hip/hip_bf16.h>

#define TILE 128
#define DD 64

typedef short short8 __attribute__((ext_vector_type(8)));
typedef float f32x4 __attribute__((ext_vector_type(4)));
typedef unsigned short us4 __attribute__((ext_vector_type(4)));

__device__ __forceinline__ float bf2f(unsigned short h) {
    union { unsigned u; float f; } v; v.u = ((unsigned)h) << 16;
    return v.f;
}
__device__ __forceinline__ unsigned short f2bf(float x) {
    __hip_bfloat16 b = __float2bfloat16(x);   // HW RNE convert (v_cvt_pk_bf16_f32)
    unsigned short u;
    __builtin_memcpy(&u, &b, 2);
    return u;
}

__global__ __launch_bounds__(256) void sqexp_kernel(
    const float* __restrict__ X1, const float* __restrict__ X2,
    const float* __restrict__ lp, const float* __restrict__ sfp,
    float* __restrict__ out, int N, int M)
{
    __shared__ unsigned short A_hi[TILE*DD], A_lo[TILE*DD], B_hi[TILE*DD], B_lo[TILE*DD];
    __shared__ float sq1[TILE], sq2[TILE];

    const int t  = threadIdx.x;
    const int n0 = blockIdx.y * TILE;
    const int m0 = blockIdx.x * TILE;

    // ---- stage both tiles: fp32 -> (hi,lo) bf16 in LDS + per-row sum of squares ----
    for (int which = 0; which < 2; ++which) {
        const float4* src = (const float4*)(which ? (X2 + (size_t)m0 * DD)
                                                  : (X1 + (size_t)n0 * DD));
        unsigned short* hi = which ? B_hi : A_hi;
        unsigned short* lo = which ? B_lo : A_lo;
        float* sq          = which ? sq2  : sq1;
        #pragma unroll
        for (int i = 0; i < 8; ++i) {
            int idx  = i * 256 + t;
            float4 f = src[idx];
            int row  = idx >> 4;
            int slot = idx & 15;
            float part = fmaf(f.x, f.x, fmaf(f.y, f.y, fmaf(f.z, f.z, f.w * f.w)));
            part += __shfl_xor(part, 1);
            part += __shfl_xor(part, 2);
            part += __shfl_xor(part, 4);
            part += __shfl_xor(part, 8);
            if ((t & 15) == 0) sq[row] = part;

            unsigned short h0 = f2bf(f.x), h1 = f2bf(f.y), h2 = f2bf(f.z), h3 = f2bf(f.w);
            us4 hv = { h0, h1, h2, h3 };
            us4 gv = { f2bf(f.x - bf2f(h0)), f2bf(f.y - bf2f(h1)),
                       f2bf(f.z - bf2f(h2)), f2bf(f.w - bf2f(h3)) };
            int byte = (row * 128 + slot * 8) ^ ((row & 7) << 4);   // XOR swizzle
            *(us4*)&hi[byte >> 1] = hv;
            *(us4*)&lo[byte >> 1] = gv;
        }
    }
    __syncthreads();

    // ---- MFMA: cross = hiA*hiB + hiA*loB + loA*hiB, operands SWAPPED so the
    //      reg index of C/D walks the N (memory-contiguous) dimension ----
    const int w  = t >> 6;
    const int l  = t & 63;
    const int wr = (w >> 1) * 64;
    const int wc = (w & 1) * 64;

    f32x4 acc[4][4] = {};
    #pragma unroll
    for (int ks = 0; ks < 2; ++ks) {
        const int kchunk = ks * 64 + ((l >> 4) * 16);
        short8 ah[4], al[4], bh[4], bl[4];
        #pragma unroll
        for (int fm = 0; fm < 4; ++fm) {
            int row  = wr + fm * 16 + (l & 15);
            int byte = (row * 128 + kchunk) ^ ((row & 7) << 4);
            ah[fm] = *(const short8*)&A_hi[byte >> 1];
            al[fm] = *(const short8*)&A_lo[byte >> 1];
        }
        #pragma unroll
        for (int fn = 0; fn < 4; ++fn) {
            int row  = wc + fn * 16 + (l & 15);
            int byte = (row * 128 + kchunk) ^ ((row & 7) << 4);
            bh[fn] = *(const short8*)&B_hi[byte >> 1];
            bl[fn] = *(const short8*)&B_lo[byte >> 1];
        }
        #pragma unroll
        for (int fm = 0; fm < 4; ++fm)
            #pragma unroll
            for (int fn = 0; fn < 4; ++fn) {
                acc[fm][fn] = __builtin_amdgcn_mfma_f32_16x16x32_bf16(bh[fn], ah[fm], acc[fm][fn], 0, 0, 0);
                acc[fm][fn] = __builtin_amdgcn_mfma_f32_16x16x32_bf16(bl[fn], ah[fm], acc[fm][fn], 0, 0, 0);
                acc[fm][fn] = __builtin_amdgcn_mfma_f32_16x16x32_bf16(bh[fn], al[fm], acc[fm][fn], 0, 0, 0);
            }
    }

    // ---- epilogue: arg = c1*(s1+s2) - 2*c1*cross, clamp arg<=0, exp, float4 store ----
    const float lv  = lp[0], sf = sfp[0];
    const float c1  = -0.5f / (lv * lv);
    const float cm2 = -2.0f * c1;
    const float amp = sf * sf;

    float a1[4];
    #pragma unroll
    for (int fm = 0; fm < 4; ++fm) a1[fm] = c1 * sq1[wr + fm * 16 + (l & 15)];
    f32x4 a2[4];
    #pragma unroll
    for (int fn = 0; fn < 4; ++fn) {
        f32x4 s = *(const f32x4*)&sq2[wc + fn * 16 + (l >> 4) * 4];
        a2[fn] = c1 * s;
    }

    #pragma unroll
    for (int fm = 0; fm < 4; ++fm) {
        size_t rbase = (size_t)(n0 + wr + fm * 16 + (l & 15)) * M + m0 + wc + (l >> 4) * 4;
        #pragma unroll
        for (int fn = 0; fn < 4; ++fn) {
            f32x4 o;
            #pragma unroll
            for (int r = 0; r < 4; ++r) {
                float arg = fminf(fmaf(cm2, acc[fm][fn][r], a1[fm] + a2[fn][r]), 0.0f);
                o[r] = amp * __expf(arg);
            }
            *(f32x4*)&out[rbase + fn * 16] = o;
        }
    }
}

extern "C" void kernel_launch(void* const* d_in, const int* in_sizes, int n_in,
                              void* d_out, int out_size, void* d_ws, size_t ws_size,
                              hipStream_t stream) {
    const float* X1 = (const float*)d_in[0];
    const float* X2 = (const float*)d_in[1];
    const float* lp = (const float*)d_in[2];
    const float* sf = (const float*)d_in[3];
    float* out = (float*)d_out;
    const int N = in_sizes[0] / DD;
    const int M = in_sizes[1] / DD;
    dim3 grid(M / TILE, N / TILE);
    sqexp_kernel<<<grid, 256, 0, stream>>>(X1, X2, lp, sf, out, N, M);
}

// Round 4
// 77.004 us; speedup vs baseline: 1.2917x; 1.2917x over previous
//
#include <hip/hip_runtime.h>
#include <hip/hip_bf16.h>

#define DD 64      // feature dim K
#define TN 64      // output rows per block  (X1 rows)
#define TM 256     // output cols per block  (X2 rows) -> 1KB-wide rows for streaming stores

typedef short short8 __attribute__((ext_vector_type(8)));
typedef unsigned short us8 __attribute__((ext_vector_type(8)));
typedef float f32x4 __attribute__((ext_vector_type(4)));

__device__ __forceinline__ float bf2f(unsigned short h) {
    union { unsigned u; float f; } v; v.u = ((unsigned)h) << 16;
    return v.f;
}
__device__ __forceinline__ unsigned short f2bf(float x) {
    __hip_bfloat16 b = __float2bfloat16(x);
    unsigned short u;
    __builtin_memcpy(&u, &b, 2);
    return u;
}

__global__ __launch_bounds__(256, 2) void sqexp_kernel(
    const float* __restrict__ X1, const float* __restrict__ X2,
    const float* __restrict__ lp, const float* __restrict__ sfp,
    float* __restrict__ out, int N, int M)
{
    // B hi/lo tiles (2x32KB) during MFMA phase; SAME 64KB aliased as the f32
    // output staging tile during the store phase.
    __shared__ __align__(16) unsigned char ldsbuf[TM * DD * 2 * 2];
    __shared__ float sq1[TN];
    __shared__ float sq2[TM];

    unsigned short* Bh = (unsigned short*)ldsbuf;
    unsigned short* Bl = (unsigned short*)(ldsbuf + 32768);

    const int t    = threadIdx.x;
    const int w    = t >> 6;
    const int lane = t & 63;
    const int n0   = blockIdx.y * TN;
    const int m0   = blockIdx.x * TM;

    const int wr = (w >> 1) * 32;    // wave's row offset   (2x2 wave grid: 32 rows x 128 cols)
    const int wc = (w & 1) * 128;    // wave's col offset

    // ---- B staging: one X2 row per thread (rows are L2-resident) ----
    const float4* Bp = (const float4*)(X2 + (size_t)(m0 + t) * DD);
    float4 bv[16];
    #pragma unroll
    for (int j = 0; j < 16; ++j) bv[j] = Bp[j];

    // ---- A fragments straight into registers (no LDS) ----
    short8 ah[2][2], al[2][2];       // [fm][ks]
    float sqa[2];
    #pragma unroll
    for (int fm = 0; fm < 2; ++fm) {
        const int row = n0 + wr + fm * 16 + (lane & 15);
        const float4* Ap = (const float4*)(X1 + (size_t)row * DD) + (lane >> 4) * 2;
        float p = 0.0f;
        #pragma unroll
        for (int ks = 0; ks < 2; ++ks) {
            float4 f0 = Ap[ks * 8];
            float4 f1 = Ap[ks * 8 + 1];
            float xs[8] = { f0.x, f0.y, f0.z, f0.w, f1.x, f1.y, f1.z, f1.w };
            us8 hv, lv;
            #pragma unroll
            for (int e = 0; e < 8; ++e) {
                p = fmaf(xs[e], xs[e], p);
                unsigned short h = f2bf(xs[e]);
                hv[e] = h;
                lv[e] = f2bf(xs[e] - bf2f(h));
            }
            __builtin_memcpy(&ah[fm][ks], &hv, 16);
            __builtin_memcpy(&al[fm][ks], &lv, 16);
        }
        p += __shfl_xor(p, 16);
        p += __shfl_xor(p, 32);
        sqa[fm] = p;                 // full row sum-of-squares (replicated over k-groups)
    }

    // sq2: in-thread (one row per thread); sq1: lanes 0-15 of even waves
    {
        float s2 = 0.0f;
        #pragma unroll
        for (int j = 0; j < 16; ++j)
            s2 += fmaf(bv[j].x, bv[j].x, fmaf(bv[j].y, bv[j].y,
                  fmaf(bv[j].z, bv[j].z, bv[j].w * bv[j].w)));
        sq2[t] = s2;
        if ((w & 1) == 0 && (lane >> 4) == 0) {
            sq1[wr + 0 * 16 + lane] = sqa[0];
            sq1[wr + 1 * 16 + lane] = sqa[1];
        }
    }

    // B -> hi/lo bf16 in LDS, XOR-swizzled 16B chunks (row stride 128B)
    #pragma unroll
    for (int c = 0; c < 8; ++c) {
        float4 f0 = bv[2 * c], f1 = bv[2 * c + 1];
        float xs[8] = { f0.x, f0.y, f0.z, f0.w, f1.x, f1.y, f1.z, f1.w };
        us8 hv, lv;
        #pragma unroll
        for (int e = 0; e < 8; ++e) {
            unsigned short h = f2bf(xs[e]);
            hv[e] = h;
            lv[e] = f2bf(xs[e] - bf2f(h));
        }
        int byte = t * 128 + ((c * 16) ^ ((t & 7) << 4));
        *(us8*)&Bh[byte >> 1] = hv;
        *(us8*)&Bl[byte >> 1] = lv;
    }
    __syncthreads();

    // ---- MFMA: cross = hiA*hiB + hiA*loB + loA*hiB (operands swapped:
    //      intrinsic-A = B-tile so C/D reg index walks the M/contiguous dim) ----
    f32x4 acc[2][8] = {};
    #pragma unroll
    for (int ks = 0; ks < 2; ++ks) {
        #pragma unroll
        for (int fn = 0; fn < 8; ++fn) {
            int brow = wc + fn * 16 + (lane & 15);
            int byte = brow * 128 + (((ks * 64) + (lane >> 4) * 16) ^ ((brow & 7) << 4));
            short8 bh = *(const short8*)&Bh[byte >> 1];
            short8 bl = *(const short8*)&Bl[byte >> 1];
            #pragma unroll
            for (int fm = 0; fm < 2; ++fm) {
                acc[fm][fn] = __builtin_amdgcn_mfma_f32_16x16x32_bf16(bh, ah[fm][ks], acc[fm][fn], 0, 0, 0);
                acc[fm][fn] = __builtin_amdgcn_mfma_f32_16x16x32_bf16(bl, ah[fm][ks], acc[fm][fn], 0, 0, 0);
                acc[fm][fn] = __builtin_amdgcn_mfma_f32_16x16x32_bf16(bh, al[fm][ks], acc[fm][fn], 0, 0, 0);
            }
        }
    }
    __syncthreads();   // all B-LDS reads done before aliasing as out-tile

    // ---- epilogue: exp -> out-LDS (swizzled) ----
    const float lv_  = lp[0], sf = sfp[0];
    const float c1   = -0.5f / (lv_ * lv_);
    const float cm2  = -2.0f * c1;
    const float amp  = sf * sf;

    float a1[2];
    #pragma unroll
    for (int fm = 0; fm < 2; ++fm) a1[fm] = c1 * sq1[wr + fm * 16 + (lane & 15)];

    #pragma unroll
    for (int fn = 0; fn < 8; ++fn) {
        f32x4 s = *(const f32x4*)&sq2[wc + fn * 16 + (lane >> 4) * 4];
        f32x4 a2 = c1 * s;
        #pragma unroll
        for (int fm = 0; fm < 2; ++fm) {
            f32x4 o;
            #pragma unroll
            for (int r = 0; r < 4; ++r) {
                float arg = fminf(fmaf(cm2, acc[fm][fn][r], a1[fm] + a2[r]), 0.0f);
                o[r] = amp * __expf(arg);
            }
            int R = wr + fm * 16 + (lane & 15);
            int C = wc + fn * 16 + (lane >> 4) * 4;
            int byte = R * 1024 + ((C * 4) ^ ((R & 7) << 4));
            *(f32x4*)(ldsbuf + byte) = o;
        }
    }
    __syncthreads();

    // ---- streaming store: one wave instr = one full contiguous 1KB output row ----
    // LDS physical chunk (lane ^ (R&7)) holds LOGICAL chunk lane (write swizzle
    // inverted on the LDS-read side ONLY); global column is the logical 4*lane.
    #pragma unroll
    for (int i = 0; i < 16; ++i) {
        int R = w * 16 + i;
        f32x4 v = *(const f32x4*)(ldsbuf + R * 1024 + ((lane ^ (R & 7)) * 16));
        size_t off = (size_t)(n0 + R) * M + m0 + 4 * lane;
        *(f32x4*)&out[off] = v;
    }
}

extern "C" void kernel_launch(void* const* d_in, const int* in_sizes, int n_in,
                              void* d_out, int out_size, void* d_ws, size_t ws_size,
                              hipStream_t stream) {
    const float* X1 = (const float*)d_in[0];
    const float* X2 = (const float*)d_in[1];
    const float* lp = (const float*)d_in[2];
    const float* sf = (const float*)d_in[3];
    float* out = (float*)d_out;
    const int N = in_sizes[0] / DD;
    const int M = in_sizes[1] / DD;
    dim3 grid(M / TM, N / TN);
    sqexp_kernel<<<grid, 256, 0, stream>>>(X1, X2, lp, sf, out, N, M);
}

// Round 5
// 76.798 us; speedup vs baseline: 1.2952x; 1.0027x over previous
//
#include <hip/hip_runtime.h>
#include <hip/hip_bf16.h>

#define DD 64      // feature dim K
#define TN 64      // output rows per block  (X1 rows)
#define TM 256     // output cols per block  (X2 rows) -> 1KB-wide rows for streaming stores

typedef short short8 __attribute__((ext_vector_type(8)));
typedef unsigned short us8 __attribute__((ext_vector_type(8)));
typedef float f32x4 __attribute__((ext_vector_type(4)));

__device__ __forceinline__ float bf2f(unsigned short h) {
    union { unsigned u; float f; } v; v.u = ((unsigned)h) << 16;
    return v.f;
}
__device__ __forceinline__ unsigned short f2bf(float x) {
    __hip_bfloat16 b = __float2bfloat16(x);
    unsigned short u;
    __builtin_memcpy(&u, &b, 2);
    return u;
}

__global__ __launch_bounds__(256, 2) void sqexp_kernel(
    const float* __restrict__ X1, const float* __restrict__ X2,
    const float* __restrict__ lp, const float* __restrict__ sfp,
    float* __restrict__ out, int N, int M)
{
    // B hi/lo tiles (2x32KB) during MFMA phase; SAME 64KB aliased as the f32
    // output staging tile during the store phase.
    __shared__ __align__(16) unsigned char ldsbuf[TM * DD * 2 * 2];
    __shared__ float sq1[TN];
    __shared__ float sq2[TM];

    unsigned short* Bh = (unsigned short*)ldsbuf;
    unsigned short* Bl = (unsigned short*)(ldsbuf + 32768);

    const int t    = threadIdx.x;
    const int w    = t >> 6;
    const int lane = t & 63;

    // ---- XCD-aware swizzle: 4096 blocks, 8 XCDs. XCD k owns newflat
    //      [512k, 512k+512) = rows [1024k, 1024k+1024) -> one contiguous
    //      33.5MB output slab per XCD; bx-fast inside (A-band L2 reuse). ----
    {
    }
    const int flat  = blockIdx.y * gridDim.x + blockIdx.x;
    const int nflat = (flat & 7) * 512 + (flat >> 3);
    const int bx    = nflat & 31;     // 32 column panels
    const int by    = nflat >> 5;     // 128 row bands
    const int n0    = by * TN;
    const int m0    = bx * TM;

    // ---- B staging: one X2 row per thread (rows are L2-resident) ----
    const float4* Bp = (const float4*)(X2 + (size_t)(m0 + t) * DD);
    float4 bv[16];
    #pragma unroll
    for (int j = 0; j < 16; ++j) bv[j] = Bp[j];

    const int wr = (w >> 1) * 32;    // wave's row offset   (2x2 wave grid: 32 rows x 128 cols)
    const int wc = (w & 1) * 128;    // wave's col offset

    // ---- A fragments straight into registers (no LDS) ----
    short8 ah[2][2], al[2][2];       // [fm][ks]
    float sqa[2];
    #pragma unroll
    for (int fm = 0; fm < 2; ++fm) {
        const int row = n0 + wr + fm * 16 + (lane & 15);
        const float4* Ap = (const float4*)(X1 + (size_t)row * DD) + (lane >> 4) * 2;
        float p = 0.0f;
        #pragma unroll
        for (int ks = 0; ks < 2; ++ks) {
            float4 f0 = Ap[ks * 8];
            float4 f1 = Ap[ks * 8 + 1];
            float xs[8] = { f0.x, f0.y, f0.z, f0.w, f1.x, f1.y, f1.z, f1.w };
            us8 hv, lv;
            #pragma unroll
            for (int e = 0; e < 8; ++e) {
                p = fmaf(xs[e], xs[e], p);
                unsigned short h = f2bf(xs[e]);
                hv[e] = h;
                lv[e] = f2bf(xs[e] - bf2f(h));
            }
            __builtin_memcpy(&ah[fm][ks], &hv, 16);
            __builtin_memcpy(&al[fm][ks], &lv, 16);
        }
        p += __shfl_xor(p, 16);
        p += __shfl_xor(p, 32);
        sqa[fm] = p;                 // full row sum-of-squares (replicated over k-groups)
    }

    // sq2: in-thread (one row per thread); sq1: lanes 0-15 of even waves
    {
        float s2 = 0.0f;
        #pragma unroll
        for (int j = 0; j < 16; ++j)
            s2 += fmaf(bv[j].x, bv[j].x, fmaf(bv[j].y, bv[j].y,
                  fmaf(bv[j].z, bv[j].z, bv[j].w * bv[j].w)));
        sq2[t] = s2;
        if ((w & 1) == 0 && (lane >> 4) == 0) {
            sq1[wr + 0 * 16 + lane] = sqa[0];
            sq1[wr + 1 * 16 + lane] = sqa[1];
        }
    }

    // B -> hi/lo bf16 in LDS, XOR-swizzled 16B chunks (row stride 128B)
    #pragma unroll
    for (int c = 0; c < 8; ++c) {
        float4 f0 = bv[2 * c], f1 = bv[2 * c + 1];
        float xs[8] = { f0.x, f0.y, f0.z, f0.w, f1.x, f1.y, f1.z, f1.w };
        us8 hv, lv;
        #pragma unroll
        for (int e = 0; e < 8; ++e) {
            unsigned short h = f2bf(xs[e]);
            hv[e] = h;
            lv[e] = f2bf(xs[e] - bf2f(h));
        }
        int byte = t * 128 + ((c * 16) ^ ((t & 7) << 4));
        *(us8*)&Bh[byte >> 1] = hv;
        *(us8*)&Bl[byte >> 1] = lv;
    }
    __syncthreads();

    // ---- MFMA: cross = hiA*hiB + hiA*loB + loA*hiB (operands swapped:
    //      intrinsic-A = B-tile so C/D reg index walks the M/contiguous dim) ----
    f32x4 acc[2][8] = {};
    #pragma unroll
    for (int ks = 0; ks < 2; ++ks) {
        #pragma unroll
        for (int fn = 0; fn < 8; ++fn) {
            int brow = wc + fn * 16 + (lane & 15);
            int byte = brow * 128 + (((ks * 64) + (lane >> 4) * 16) ^ ((brow & 7) << 4));
            short8 bh = *(const short8*)&Bh[byte >> 1];
            short8 bl = *(const short8*)&Bl[byte >> 1];
            #pragma unroll
            for (int fm = 0; fm < 2; ++fm) {
                acc[fm][fn] = __builtin_amdgcn_mfma_f32_16x16x32_bf16(bh, ah[fm][ks], acc[fm][fn], 0, 0, 0);
                acc[fm][fn] = __builtin_amdgcn_mfma_f32_16x16x32_bf16(bl, ah[fm][ks], acc[fm][fn], 0, 0, 0);
                acc[fm][fn] = __builtin_amdgcn_mfma_f32_16x16x32_bf16(bh, al[fm][ks], acc[fm][fn], 0, 0, 0);
            }
        }
    }
    __syncthreads();   // all B-LDS reads done before aliasing as out-tile

    // ---- epilogue: exp -> out-LDS (swizzled) ----
    const float lv_  = lp[0], sf = sfp[0];
    const float c1   = -0.5f / (lv_ * lv_);
    const float cm2  = -2.0f * c1;
    const float amp  = sf * sf;

    float a1[2];
    #pragma unroll
    for (int fm = 0; fm < 2; ++fm) a1[fm] = c1 * sq1[wr + fm * 16 + (lane & 15)];

    #pragma unroll
    for (int fn = 0; fn < 8; ++fn) {
        f32x4 s = *(const f32x4*)&sq2[wc + fn * 16 + (lane >> 4) * 4];
        f32x4 a2 = c1 * s;
        #pragma unroll
        for (int fm = 0; fm < 2; ++fm) {
            f32x4 o;
            #pragma unroll
            for (int r = 0; r < 4; ++r) {
                float arg = fminf(fmaf(cm2, acc[fm][fn][r], a1[fm] + a2[r]), 0.0f);
                o[r] = amp * __expf(arg);
            }
            int R = wr + fm * 16 + (lane & 15);
            int C = wc + fn * 16 + (lane >> 4) * 4;
            int byte = R * 1024 + ((C * 4) ^ ((R & 7) << 4));
            *(f32x4*)(ldsbuf + byte) = o;
        }
    }
    __syncthreads();

    // ---- streaming store: one wave instr = one full contiguous 1KB output row.
    //      Batched 4 rows per group (4 ds_reads -> 4 stores) for issue ILP.
    //      Nontemporal: output is never re-read, skip L2 allocation. ----
    #pragma unroll
    for (int g = 0; g < 4; ++g) {
        f32x4 v[4];
        #pragma unroll
        for (int i = 0; i < 4; ++i) {
            int R = w * 16 + g * 4 + i;
            v[i] = *(const f32x4*)(ldsbuf + R * 1024 + ((lane ^ (R & 7)) * 16));
        }
        #pragma unroll
        for (int i = 0; i < 4; ++i) {
            int R = w * 16 + g * 4 + i;
            size_t off = (size_t)(n0 + R) * M + m0 + 4 * lane;
            __builtin_nontemporal_store(v[i], (f32x4*)&out[off]);
        }
    }
}

extern "C" void kernel_launch(void* const* d_in, const int* in_sizes, int n_in,
                              void* d_out, int out_size, void* d_ws, size_t ws_size,
                              hipStream_t stream) {
    const float* X1 = (const float*)d_in[0];
    const float* X2 = (const float*)d_in[1];
    const float* lp = (const float*)d_in[2];
    const float* sf = (const float*)d_in[3];
    float* out = (float*)d_out;
    const int N = in_sizes[0] / DD;
    const int M = in_sizes[1] / DD;
    dim3 grid(M / TM, N / TN);   // 32 x 128 = 4096 blocks (swizzled in-kernel)
    sqexp_kernel<<<grid, 256, 0, stream>>>(X1, X2, lp, sf, out, N, M);
}